// Round 10
// baseline (349.852 us; speedup 1.0000x reference)
//
#include <hip/hip_runtime.h>
#include <hip/hip_bf16.h>
#include <stdint.h>

#define TT 512
#define NB 128
#define EM 256
#define UN 256

typedef short bf16x8 __attribute__((ext_vector_type(8)));
typedef float floatx4 __attribute__((ext_vector_type(4)));
typedef _Float16 half8 __attribute__((ext_vector_type(8)));
typedef int v8i __attribute__((ext_vector_type(8)));

#define SCALE_A 0x7D7D7D7DU   // e8m0 125 = 2^-2  (h stored as 4*h)
#define SCALE_B 0x7B7B7B7BU   // e8m0 123 = 2^-4  (U stored as 16*U)

// barrier without vmcnt drain: LDS-ordered only (no VMEM in scan steady state)
#define BAR() asm volatile("s_waitcnt lgkmcnt(0)\n\ts_barrier" ::: "memory")

__device__ inline unsigned short f2bf(float f) {
    union { float f; uint32_t u; } v; v.f = f;
    uint32_t r = v.u + 0x7fffu + ((v.u >> 16) & 1u);
    return (unsigned short)(r >> 16);
}
__device__ inline float bf2f(unsigned short b) {
    union { uint32_t u; float f; } v; v.u = ((uint32_t)b) << 16;
    return v.f;
}
__device__ inline unsigned char f2fp8(float f) {
    int pk = __builtin_amdgcn_cvt_pk_fp8_f32(f, f, 0, false);  // OCP e4m3 on gfx950
    return (unsigned char)(pk & 0xff);
}
__device__ inline float fp8d(unsigned char b) {   // e4m3fn decode (head only)
    int s = b >> 7, e = (b >> 3) & 15, m = b & 7;
    float v = e ? ldexpf((float)(8 + m), e - 10) : ldexpf((float)m, -9);
    return s ? -v : v;
}

// ---------------------------------------------------------------------------
// Kernel 1: blocks 0..31: W -> bf16 B-frags (K=32 layout, for k_gemm).
//           blocks 32..63: U*16 -> fp8 e4m3 B-frags (K=128 layout, for k_rnn).
// ---------------------------------------------------------------------------
__global__ void k_pack(const float* __restrict__ W, const float* __restrict__ U,
                       unsigned short* __restrict__ wfrag, unsigned char* __restrict__ ufrag8) {
    int bid = blockIdx.x;
    if (bid < 32) {
        int idx = bid * 256 + threadIdx.x;  // 0..8191
        int lane = idx & 63;
        int tile = idx >> 6;            // kt*16 + nt
        int nt = tile & 15, kt = tile >> 4;
        int u  = nt * 16 + (lane & 15);
        int e0 = kt * 32 + (lane >> 4) * 8;
        unsigned short* dst = wfrag + (size_t)idx * 8;
        #pragma unroll
        for (int j = 0; j < 8; j++) dst[j] = f2bf(W[u * EM + e0 + j]);
    } else {
        int idx = (bid - 32) * 256 + threadIdx.x;  // 0..8191
        int jg   = idx & 3;             // 8-byte group within the 32B lane slice
        int lane = (idx >> 2) & 63;
        int tile = idx >> 8;            // kh*16 + nt, 0..31
        int nt = tile & 15, kh = tile >> 4;
        int u  = nt * 16 + (lane & 15);
        int k0 = kh * 128 + (lane >> 4) * 32 + jg * 8;
        unsigned char* dst = ufrag8 + ((size_t)tile * 64 + lane) * 32 + jg * 8;
        #pragma unroll
        for (int j = 0; j < 8; j++) dst[j] = f2fp8(16.f * U[u * UN + k0 + j]);
    }
}

// ---------------------------------------------------------------------------
// Kernel 2: xw[b][t][u] = sum_e emb[sent[b][t]][e] * W[u][e], bf16 out.
// (R8 version: LDS-transposed coalesced stores)
// ---------------------------------------------------------------------------
__global__ __launch_bounds__(256, 2) void k_gemm(
    const int* __restrict__ sent, const float* __restrict__ emb,
    const unsigned short* __restrict__ wfrag, unsigned short* __restrict__ xw)
{
    __shared__ unsigned short gt[64][264];
    int w    = threadIdx.x >> 6;
    int lane = threadIdx.x & 63;
    int m  = lane & 15;
    int kg = lane >> 4;
    int row = blockIdx.x * 64 + w * 16 + m;
    int tok = sent[row];
    const float* arow = emb + (size_t)tok * EM;

    bf16x8 a[8];
    #pragma unroll
    for (int kt = 0; kt < 8; kt++) {
        const float* p = arow + kt * 32 + kg * 8;
        float4 f0 = *(const float4*)p;
        float4 f1 = *(const float4*)(p + 4);
        bf16x8 t;
        t[0] = (short)f2bf(f0.x); t[1] = (short)f2bf(f0.y);
        t[2] = (short)f2bf(f0.z); t[3] = (short)f2bf(f0.w);
        t[4] = (short)f2bf(f1.x); t[5] = (short)f2bf(f1.y);
        t[6] = (short)f2bf(f1.z); t[7] = (short)f2bf(f1.w);
        a[kt] = t;
    }

    floatx4 acc[16];
    #pragma unroll
    for (int nt = 0; nt < 16; nt++) acc[nt] = floatx4{0.f, 0.f, 0.f, 0.f};

    #pragma unroll
    for (int kt = 0; kt < 8; kt++) {
        #pragma unroll
        for (int nt = 0; nt < 16; nt++) {
            bf16x8 bfr = *(const bf16x8*)(wfrag + ((size_t)(kt * 16 + nt) * 64 + lane) * 8);
            acc[nt] = __builtin_amdgcn_mfma_f32_16x16x32_bf16(a[kt], bfr, acc[nt], 0, 0, 0);
        }
    }

    int rloc = w * 16 + kg * 4;
    #pragma unroll
    for (int nt = 0; nt < 16; nt++) {
        #pragma unroll
        for (int r = 0; r < 4; r++) {
            gt[rloc + r][nt * 16 + m] = f2bf(acc[nt][r]);
        }
    }
    __syncthreads();

    int rowbase = blockIdx.x * 64;
    #pragma unroll
    for (int r2 = 0; r2 < 16; r2++) {
        int rr = w * 16 + r2;
        uint2 v = *(const uint2*)&gt[rr][lane * 4];
        *(uint2*)(xw + (size_t)(rowbase + rr) * UN + lane * 4) = v;
    }
}

// ---------------------------------------------------------------------------
// Kernel 3 (v9): MX-fp8 K=128 scan with INDEPENDENT accumulators.
// Identical to v8 except each K-half gets its own accumulator so all 8
// scaled MFMAs per wave per step are chain-free (latency exposed once,
// not twice); z = accA[0] + accB[0] in VALU.
// ---------------------------------------------------------------------------
__global__ __launch_bounds__(256, 1) void k_rnn(
    const unsigned char* __restrict__ ufrag8, const unsigned short* __restrict__ xw,
    const float* __restrict__ W1, const float* __restrict__ b1,
    const float* __restrict__ W2, const float* __restrict__ b2,
    float* __restrict__ out)
{
    __shared__ __align__(16) unsigned char hb8[2][256];
    __shared__ __align__(16) unsigned short xstage[64 * 256];   // 32 KB chunk
    __shared__ float hid[32];
    const int t    = threadIdx.x;
    const int lane = t & 63;
    const int w    = t >> 6;
    const int kg   = lane >> 4;
    const int b    = blockIdx.x;

    // U fp8 B-frags -> registers: ufr8[q][kh], tile nt = 4w+q, k-half kh
    v8i ufr8[4][2];
    #pragma unroll
    for (int q = 0; q < 4; q++) {
        #pragma unroll
        for (int kh = 0; kh < 2; kh++) {
            const uint4* p = (const uint4*)(ufrag8 + ((size_t)(kh * 16 + 4 * w + q) * 64 + lane) * 32);
            union { uint4 u4[2]; v8i v; } cvt;
            cvt.u4[0] = p[0]; cvt.u4[1] = p[1];
            ufr8[q][kh] = cvt.v;
        }
    }

    const unsigned short* xwb = xw + (size_t)b * TT * UN;
    const int roff = w * 512 + lane * 8;

    // stage chunk 0 (steps 0..63)
    uint4 xr[8];
    #pragma unroll
    for (int p = 0; p < 8; p++) xr[p] = *(const uint4*)(xwb + roff + p * 2048);
    #pragma unroll
    for (int p = 0; p < 8; p++) *(uint4*)&xstage[roff + p * 2048] = xr[p];

    hb8[0][t] = 0; hb8[1][t] = 0;
    __syncthreads();

    int cur = 0;
    const float c3 = -0.33333334f, c5 = 0.13333334f, c7 = -0.05396825f, c9 = 0.02186949f;
    const floatx4 zero4 = {0.f, 0.f, 0.f, 0.f};
    const int sel = lane >> 4;

    for (int s = 0; s < TT; s++) {
        const int ls = s & 63;
        float xf = bf2f(xstage[ls * 256 + t]);

        // A-frags (fp8, 4*h): lane reads 32B at kg*32 for each k-half (broadcast)
        const unsigned char* hc = hb8[cur];
        union { uint4 u4[2]; v8i v; } A0, A1;
        A0.u4[0] = *(const uint4*)(hc + kg * 32);
        A0.u4[1] = *(const uint4*)(hc + kg * 32 + 16);
        A1.u4[0] = *(const uint4*)(hc + 128 + kg * 32);
        A1.u4[1] = *(const uint4*)(hc + 128 + kg * 32 + 16);

        // 8 fully independent scaled MFMAs (no accumulator chains)
        floatx4 za[4], zb[4];
        #pragma unroll
        for (int q = 0; q < 4; q++) {
            za[q] = __builtin_amdgcn_mfma_scale_f32_16x16x128_f8f6f4(
                        A0.v, ufr8[q][0], zero4, 0, 0, 0, SCALE_A, 0, SCALE_B);
            zb[q] = __builtin_amdgcn_mfma_scale_f32_16x16x128_f8f6f4(
                        A1.v, ufr8[q][1], zero4, 0, 0, 0, SCALE_A, 0, SCALE_B);
        }

        float z[4];
        #pragma unroll
        for (int q = 0; q < 4; q++) z[q] = za[q][0] + zb[q][0];

        float zz = (sel == 0) ? z[0] : (sel == 1) ? z[1] : (sel == 2) ? z[2] : z[3];
        zz += xf;

        float hn;
        if (__builtin_expect(fabsf(zz) > 0.75f, 0)) {
            float e = __expf(2.f * zz);
            hn = 1.f - 2.f * __builtin_amdgcn_rcpf(e + 1.f);
        } else {
            float x2f = zz * zz;
            float p = fmaf(x2f, c9, c7);
            p = fmaf(x2f, p, c5);
            p = fmaf(x2f, p, c3);
            hn = fmaf(zz * x2f, p, zz);
        }

        hb8[cur ^ 1][t] = f2fp8(4.f * hn);

        if (ls == 60 && s + 68 <= TT) {
            const unsigned short* cb = xwb + (size_t)(s + 4) * UN;
            #pragma unroll
            for (int p = 0; p < 8; p++) xr[p] = *(const uint4*)(cb + roff + p * 2048);
        }
        if (ls == 63 && s + 65 <= TT) {
            BAR();
            #pragma unroll
            for (int p = 0; p < 8; p++) *(uint4*)&xstage[roff + p * 2048] = xr[p];
        }
        BAR();
        cur ^= 1;
    }

    // ---- head: hidden = relu(h @ W1 + b1); logits; softmax (h = fp8/4)
    if (t < 32) {
        float a = b1[t];
        for (int k = 0; k < 256; k++) a += 0.25f * fp8d(hb8[cur][k]) * W1[k * 32 + t];
        hid[t] = fmaxf(a, 0.f);
    }
    __syncthreads();
    if (t == 0) {
        float l0 = b2[0], l1 = b2[1];
        #pragma unroll
        for (int i = 0; i < 32; i++) {
            float hv = hid[i];
            l0 += hv * W2[2 * i];
            l1 += hv * W2[2 * i + 1];
        }
        float mx2 = fmaxf(l0, l1);
        float e0 = __expf(l0 - mx2), e1 = __expf(l1 - mx2);
        float inv = 1.f / (e0 + e1);
        out[2 * b]     = e0 * inv;
        out[2 * b + 1] = e1 * inv;
    }
}

extern "C" void kernel_launch(void* const* d_in, const int* in_sizes, int n_in,
                              void* d_out, int out_size, void* d_ws, size_t ws_size,
                              hipStream_t stream) {
    const int*   sent = (const int*)d_in[0];
    const float* emb  = (const float*)d_in[1];
    const float* W    = (const float*)d_in[2];
    const float* U    = (const float*)d_in[3];
    const float* W1   = (const float*)d_in[4];
    const float* b1   = (const float*)d_in[5];
    const float* W2   = (const float*)d_in[6];
    const float* b2   = (const float*)d_in[7];
    float* out = (float*)d_out;

    unsigned short* xw     = (unsigned short*)d_ws;                                     // 32 MB bf16 [B][T][U]
    unsigned short* wfrag  = (unsigned short*)((char*)d_ws + (size_t)NB * TT * UN * 2); // 128 KB
    unsigned char*  ufrag8 = (unsigned char*)((char*)d_ws + (size_t)NB * TT * UN * 2 + (size_t)UN * EM * 2); // 64 KB

    k_pack<<<64, 256, 0, stream>>>(W, U, wfrag, ufrag8);
    k_gemm<<<(NB * TT) / 64, 256, 0, stream>>>(sent, emb, wfrag, xw);
    k_rnn<<<NB, 256, 0, stream>>>(ufrag8, xw, W1, b1, W2, b2, out);
}

// Round 11
// 335.124 us; speedup vs baseline: 1.0439x; 1.0439x over previous
//
#include <hip/hip_runtime.h>
#include <hip/hip_bf16.h>
#include <stdint.h>

#define TT 512
#define NB 128
#define EM 256
#define UN 256

typedef short bf16x8 __attribute__((ext_vector_type(8)));
typedef float floatx4 __attribute__((ext_vector_type(4)));
typedef int v8i __attribute__((ext_vector_type(8)));

#define SCALE_A 0x7D7D7D7DU   // e8m0 125 = 2^-2  (h stored as 4*h)
#define SCALE_B 0x7B7B7B7BU   // e8m0 123 = 2^-4  (U stored as 16*U)

// barrier without vmcnt drain: LDS-ordered only (no VMEM near barriers)
#define BAR() asm volatile("s_waitcnt lgkmcnt(0)\n\ts_barrier" ::: "memory")

__device__ inline unsigned short f2bf(float f) {
    union { float f; uint32_t u; } v; v.f = f;
    uint32_t r = v.u + 0x7fffu + ((v.u >> 16) & 1u);
    return (unsigned short)(r >> 16);
}
__device__ inline float bf2f(unsigned short b) {
    union { uint32_t u; float f; } v; v.u = ((uint32_t)b) << 16;
    return v.f;
}
__device__ inline unsigned char f2fp8(float f) {
    int pk = __builtin_amdgcn_cvt_pk_fp8_f32(f, f, 0, false);  // OCP e4m3 on gfx950
    return (unsigned char)(pk & 0xff);
}
__device__ inline float fp8d(unsigned char b) {   // e4m3fn decode (head only)
    int s = b >> 7, e = (b >> 3) & 15, m = b & 7;
    float v = e ? ldexpf((float)(8 + m), e - 10) : ldexpf((float)m, -9);
    return s ? -v : v;
}

// ---------------------------------------------------------------------------
// Kernel 1: blocks 0..31: W -> bf16 B-frags (K=32 layout, for k_gemm).
//           blocks 32..63: U*16 -> fp8 e4m3 B-frags (K=128 layout, for k_rnn).
// ---------------------------------------------------------------------------
__global__ void k_pack(const float* __restrict__ W, const float* __restrict__ U,
                       unsigned short* __restrict__ wfrag, unsigned char* __restrict__ ufrag8) {
    int bid = blockIdx.x;
    if (bid < 32) {
        int idx = bid * 256 + threadIdx.x;  // 0..8191
        int lane = idx & 63;
        int tile = idx >> 6;            // kt*16 + nt
        int nt = tile & 15, kt = tile >> 4;
        int u  = nt * 16 + (lane & 15);
        int e0 = kt * 32 + (lane >> 4) * 8;
        unsigned short* dst = wfrag + (size_t)idx * 8;
        #pragma unroll
        for (int j = 0; j < 8; j++) dst[j] = f2bf(W[u * EM + e0 + j]);
    } else {
        int idx = (bid - 32) * 256 + threadIdx.x;  // 0..8191
        int jg   = idx & 3;
        int lane = (idx >> 2) & 63;
        int tile = idx >> 8;            // kh*16 + nt, 0..31
        int nt = tile & 15, kh = tile >> 4;
        int u  = nt * 16 + (lane & 15);
        int k0 = kh * 128 + (lane >> 4) * 32 + jg * 8;
        unsigned char* dst = ufrag8 + ((size_t)tile * 64 + lane) * 32 + jg * 8;
        #pragma unroll
        for (int j = 0; j < 8; j++) dst[j] = f2fp8(16.f * U[u * UN + k0 + j]);
    }
}

// ---------------------------------------------------------------------------
// Kernel 2: xw[b][t][u] = sum_e emb[sent[b][t]][e] * W[u][e], bf16 out.
// (unchanged: LDS-transposed coalesced stores)
// ---------------------------------------------------------------------------
__global__ __launch_bounds__(256, 2) void k_gemm(
    const int* __restrict__ sent, const float* __restrict__ emb,
    const unsigned short* __restrict__ wfrag, unsigned short* __restrict__ xw)
{
    __shared__ unsigned short gt[64][264];
    int w    = threadIdx.x >> 6;
    int lane = threadIdx.x & 63;
    int m  = lane & 15;
    int kg = lane >> 4;
    int row = blockIdx.x * 64 + w * 16 + m;
    int tok = sent[row];
    const float* arow = emb + (size_t)tok * EM;

    bf16x8 a[8];
    #pragma unroll
    for (int kt = 0; kt < 8; kt++) {
        const float* p = arow + kt * 32 + kg * 8;
        float4 f0 = *(const float4*)p;
        float4 f1 = *(const float4*)(p + 4);
        bf16x8 t;
        t[0] = (short)f2bf(f0.x); t[1] = (short)f2bf(f0.y);
        t[2] = (short)f2bf(f0.z); t[3] = (short)f2bf(f0.w);
        t[4] = (short)f2bf(f1.x); t[5] = (short)f2bf(f1.y);
        t[6] = (short)f2bf(f1.z); t[7] = (short)f2bf(f1.w);
        a[kt] = t;
    }

    floatx4 acc[16];
    #pragma unroll
    for (int nt = 0; nt < 16; nt++) acc[nt] = floatx4{0.f, 0.f, 0.f, 0.f};

    #pragma unroll
    for (int kt = 0; kt < 8; kt++) {
        #pragma unroll
        for (int nt = 0; nt < 16; nt++) {
            bf16x8 bfr = *(const bf16x8*)(wfrag + ((size_t)(kt * 16 + nt) * 64 + lane) * 8);
            acc[nt] = __builtin_amdgcn_mfma_f32_16x16x32_bf16(a[kt], bfr, acc[nt], 0, 0, 0);
        }
    }

    int rloc = w * 16 + kg * 4;
    #pragma unroll
    for (int nt = 0; nt < 16; nt++) {
        #pragma unroll
        for (int r = 0; r < 4; r++) {
            gt[rloc + r][nt * 16 + m] = f2bf(acc[nt][r]);
        }
    }
    __syncthreads();

    int rowbase = blockIdx.x * 64;
    #pragma unroll
    for (int r2 = 0; r2 < 16; r2++) {
        int rr = w * 16 + r2;
        uint2 v = *(const uint2*)&gt[rr][lane * 4];
        *(uint2*)(xw + (size_t)(rowbase + rr) * UN + lane * 4) = v;
    }
}

// ---------------------------------------------------------------------------
// Kernel 3 (v11): MX-fp8 K=128 scan, 512 threads (8 waves, 2 waves/SIMD).
// Wave w (0..7) owns N-tiles 2w,2w+1 (units 32w..32w+31). Chained 2-MFMA
// accumulate per tile (R9's proven best). Lanes 0..31 own unit 32w+L
// (lanes 32..63 compute redundantly, write-predicated). 2 waves/SIMD give
// TLP to hide LDS/MFMA latency that was fully exposed at 1 wave/SIMD.
// xw staged in LDS 64 steps at a time; lgkm-only barriers.
// ---------------------------------------------------------------------------
__global__ __launch_bounds__(512, 1) void k_rnn(
    const unsigned char* __restrict__ ufrag8, const unsigned short* __restrict__ xw,
    const float* __restrict__ W1, const float* __restrict__ b1,
    const float* __restrict__ W2, const float* __restrict__ b2,
    float* __restrict__ out)
{
    __shared__ __align__(16) unsigned char hb8[2][256];
    __shared__ __align__(16) unsigned short xstage[64 * 256];   // 32 KB chunk
    __shared__ float hid[32];
    const int t    = threadIdx.x;     // 0..511
    const int lane = t & 63;
    const int w    = t >> 6;          // 0..7
    const int kg   = lane >> 4;
    const int b    = blockIdx.x;

    // U fp8 B-frags -> registers: ufr8[dt][kh], tile nt = 2w+dt
    v8i ufr8[2][2];
    #pragma unroll
    for (int dt = 0; dt < 2; dt++) {
        #pragma unroll
        for (int kh = 0; kh < 2; kh++) {
            const uint4* p = (const uint4*)(ufrag8 + ((size_t)(kh * 16 + 2 * w + dt) * 64 + lane) * 32);
            union { uint4 u4[2]; v8i v; } cvt;
            cvt.u4[0] = p[0]; cvt.u4[1] = p[1];
            ufr8[dt][kh] = cvt.v;
        }
    }

    const unsigned short* xwb = xw + (size_t)b * TT * UN;
    const int roff = t * 8;   // ushort offset of this thread's 16B refresh slice

    // stage chunk 0 (steps 0..63): 512 thr x 4 x 16B = 32 KB
    uint4 xr[4];
    #pragma unroll
    for (int p = 0; p < 4; p++) xr[p] = *(const uint4*)(xwb + roff + p * 4096);
    #pragma unroll
    for (int p = 0; p < 4; p++) *(uint4*)&xstage[roff + p * 4096] = xr[p];

    if (t < 256) { hb8[0][t] = 0; hb8[1][t] = 0; }
    __syncthreads();

    int cur = 0;
    const float c3 = -0.33333334f, c5 = 0.13333334f, c7 = -0.05396825f, c9 = 0.02186949f;
    const floatx4 zero4 = {0.f, 0.f, 0.f, 0.f};
    const int myu   = 32 * w + (lane & 31);   // unit owned (lanes 0..31 real)
    const int dtsel = (lane >> 4) & 1;        // which of my 2 tiles holds myu

    for (int s = 0; s < TT; s++) {
        const int ls = s & 63;
        float xf = bf2f(xstage[ls * 256 + myu]);

        // A-frags (fp8, 4*h): broadcast 32B reads per k-half
        const unsigned char* hc = hb8[cur];
        union { uint4 u4[2]; v8i v; } A0, A1;
        A0.u4[0] = *(const uint4*)(hc + kg * 32);
        A0.u4[1] = *(const uint4*)(hc + kg * 32 + 16);
        A1.u4[0] = *(const uint4*)(hc + 128 + kg * 32);
        A1.u4[1] = *(const uint4*)(hc + 128 + kg * 32 + 16);

        // 2 tiles, chained K=128 x2 accumulate (R9-proven form)
        float z[2];
        #pragma unroll
        for (int dt = 0; dt < 2; dt++) {
            floatx4 acc = __builtin_amdgcn_mfma_scale_f32_16x16x128_f8f6f4(
                              A0.v, ufr8[dt][0], zero4, 0, 0, 0, SCALE_A, 0, SCALE_B);
            acc = __builtin_amdgcn_mfma_scale_f32_16x16x128_f8f6f4(
                              A1.v, ufr8[dt][1], acc, 0, 0, 0, SCALE_A, 0, SCALE_B);
            z[dt] = acc[0];
        }

        float zz = (dtsel ? z[1] : z[0]) + xf;

        float hn;
        if (__builtin_expect(fabsf(zz) > 0.75f, 0)) {
            float e = __expf(2.f * zz);
            hn = 1.f - 2.f * __builtin_amdgcn_rcpf(e + 1.f);
        } else {
            float x2f = zz * zz;
            float p = fmaf(x2f, c9, c7);
            p = fmaf(x2f, p, c5);
            p = fmaf(x2f, p, c3);
            hn = fmaf(zz * x2f, p, zz);
        }

        if (lane < 32) hb8[cur ^ 1][myu] = f2fp8(4.f * hn);

        if (ls == 60 && s + 68 <= TT) {
            const unsigned short* cb = xwb + (size_t)(s + 4) * UN;
            #pragma unroll
            for (int p = 0; p < 4; p++) xr[p] = *(const uint4*)(cb + roff + p * 4096);
        }
        if (ls == 63 && s + 65 <= TT) {
            BAR();
            #pragma unroll
            for (int p = 0; p < 4; p++) *(uint4*)&xstage[roff + p * 4096] = xr[p];
        }
        BAR();
        cur ^= 1;
    }

    // ---- head: hidden = relu(h @ W1 + b1); logits; softmax (h = fp8/4)
    if (t < 32) {
        float a = b1[t];
        for (int k = 0; k < 256; k++) a += 0.25f * fp8d(hb8[cur][k]) * W1[k * 32 + t];
        hid[t] = fmaxf(a, 0.f);
    }
    __syncthreads();
    if (t == 0) {
        float l0 = b2[0], l1 = b2[1];
        #pragma unroll
        for (int i = 0; i < 32; i++) {
            float hv = hid[i];
            l0 += hv * W2[2 * i];
            l1 += hv * W2[2 * i + 1];
        }
        float mx2 = fmaxf(l0, l1);
        float e0 = __expf(l0 - mx2), e1 = __expf(l1 - mx2);
        float inv = 1.f / (e0 + e1);
        out[2 * b]     = e0 * inv;
        out[2 * b + 1] = e1 * inv;
    }
}

extern "C" void kernel_launch(void* const* d_in, const int* in_sizes, int n_in,
                              void* d_out, int out_size, void* d_ws, size_t ws_size,
                              hipStream_t stream) {
    const int*   sent = (const int*)d_in[0];
    const float* emb  = (const float*)d_in[1];
    const float* W    = (const float*)d_in[2];
    const float* U    = (const float*)d_in[3];
    const float* W1   = (const float*)d_in[4];
    const float* b1   = (const float*)d_in[5];
    const float* W2   = (const float*)d_in[6];
    const float* b2   = (const float*)d_in[7];
    float* out = (float*)d_out;

    unsigned short* xw     = (unsigned short*)d_ws;                                     // 32 MB bf16 [B][T][U]
    unsigned short* wfrag  = (unsigned short*)((char*)d_ws + (size_t)NB * TT * UN * 2); // 128 KB
    unsigned char*  ufrag8 = (unsigned char*)((char*)d_ws + (size_t)NB * TT * UN * 2 + (size_t)UN * EM * 2); // 64 KB

    k_pack<<<64, 256, 0, stream>>>(W, U, wfrag, ufrag8);
    k_gemm<<<(NB * TT) / 64, 256, 0, stream>>>(sent, emb, wfrag, xw);
    k_rnn<<<NB, 512, 0, stream>>>(ufrag8, xw, W1, b1, W2, b2, out);
}

// Round 13
// 302.473 us; speedup vs baseline: 1.1566x; 1.1079x over previous
//
#include <hip/hip_runtime.h>
#include <hip/hip_bf16.h>
#include <stdint.h>

#define TT 512
#define NB 128
#define EM 256
#define UN 256

typedef float floatx4 __attribute__((ext_vector_type(4)));
typedef int v8i __attribute__((ext_vector_type(8)));

#define SCALE_Q 0x7B7B7B7BU   // e8m0 123 = 2^-4 (operands stored x16)
#define SCALE_A 0x7D7D7D7DU   // e8m0 125 = 2^-2  (h stored as 4*h)

// barrier without vmcnt drain: LDS-ordered only (no VMEM near barriers)
#define BAR() asm volatile("s_waitcnt lgkmcnt(0)\n\ts_barrier" ::: "memory")

__device__ inline unsigned short f2bf(float f) {
    union { float f; uint32_t u; } v; v.f = f;
    uint32_t r = v.u + 0x7fffu + ((v.u >> 16) & 1u);
    return (unsigned short)(r >> 16);
}
__device__ inline unsigned char f2fp8(float f) {
    int pk = __builtin_amdgcn_cvt_pk_fp8_f32(f, f, 0, false);  // OCP e4m3 on gfx950
    return (unsigned char)(pk & 0xff);
}
// byte-select must be an immediate: shift word so target byte is byte 0
__device__ inline float fp8dec(uint32_t word, int sel) {
#if defined(__has_builtin)
#if __has_builtin(__builtin_amdgcn_cvt_f32_fp8)
    return __builtin_amdgcn_cvt_f32_fp8(word >> (8 * sel), 0);
#else
    unsigned char b = (word >> (8 * sel)) & 0xff;
    int s = b >> 7, e = (b >> 3) & 15, m = b & 7;
    float v = e ? ldexpf((float)(8 + m), e - 10) : ldexpf((float)m, -9);
    return s ? -v : v;
#endif
#else
    unsigned char b = (word >> (8 * sel)) & 0xff;
    int s = b >> 7, e = (b >> 3) & 15, m = b & 7;
    float v = e ? ldexpf((float)(8 + m), e - 10) : ldexpf((float)m, -9);
    return s ? -v : v;
#endif
}

// ---------------------------------------------------------------------------
// Kernel 1: blocks 0..31: W*16 -> fp8 B-frags (K=128 layout, for k_gemm).
//           blocks 32..63: U*16 -> fp8 B-frags (same layout, for k_rnn).
// frag[((kh*16+nt)*64+lane)*32 + j] = fp8(16*M[nt*16+(lane&15)][kh*128+(lane>>4)*32+j])
// ---------------------------------------------------------------------------
__global__ void k_pack(const float* __restrict__ W, const float* __restrict__ U,
                       unsigned char* __restrict__ wfrag8, unsigned char* __restrict__ ufrag8) {
    int bid = blockIdx.x;
    const float* src = (bid < 32) ? W : U;
    unsigned char* dstbase = (bid < 32) ? wfrag8 : ufrag8;
    int idx = (bid & 31) * 256 + threadIdx.x;  // 0..8191
    int jg   = idx & 3;
    int lane = (idx >> 2) & 63;
    int tile = idx >> 8;            // kh*16 + nt, 0..31
    int nt = tile & 15, kh = tile >> 4;
    int u  = nt * 16 + (lane & 15);
    int k0 = kh * 128 + (lane >> 4) * 32 + jg * 8;
    unsigned char* dst = dstbase + ((size_t)tile * 64 + lane) * 32 + jg * 8;
    #pragma unroll
    for (int j = 0; j < 8; j++) dst[j] = f2fp8(16.f * src[u * EM + k0 + j]);
}

// ---------------------------------------------------------------------------
// Kernel 2 (fp8): xw[b][t][u] = emb[sent]·W^T via mfma_scale 16x16x128.
// 1024 blocks x 256 thr. Wave w: rows (timesteps) w*16..w*16+15.
// A = gathered emb row quantized fp8 x16 in regs (2 k-halves x 32 B/lane).
// B = wfrag8 (L2-hot). 32 MFMA/wave (16 nt x 2 kh chained). xw stored fp8 x16
// via LDS transpose -> coalesced dword stores (16 MB total).
// ---------------------------------------------------------------------------
__global__ __launch_bounds__(256, 2) void k_gemm(
    const int* __restrict__ sent, const float* __restrict__ emb,
    const unsigned char* __restrict__ wfrag8, unsigned char* __restrict__ xw8)
{
    __shared__ unsigned char gt[64][272];   // 64 rows x 256 cols fp8, +16 pad
    int w    = threadIdx.x >> 6;
    int lane = threadIdx.x & 63;
    int m  = lane & 15;
    int kg = lane >> 4;
    int row = blockIdx.x * 64 + w * 16 + m;
    int tok = sent[row];
    const float* arow = emb + (size_t)tok * EM;

    // A-frags: quantize this lane's 2 x 32-float slices to fp8 x16
    union { uint32_t d[8]; v8i v; } A[2];
    #pragma unroll
    for (int kh = 0; kh < 2; kh++) {
        const float* p = arow + kh * 128 + kg * 32;
        #pragma unroll
        for (int d = 0; d < 8; d++) {
            float4 f = *(const float4*)(p + 4 * d);
            int pk = __builtin_amdgcn_cvt_pk_fp8_f32(16.f * f.x, 16.f * f.y, 0, false);
            pk     = __builtin_amdgcn_cvt_pk_fp8_f32(16.f * f.z, 16.f * f.w, pk, true);
            A[kh].d[d] = (uint32_t)pk;
        }
    }

    const floatx4 zero4 = {0.f, 0.f, 0.f, 0.f};
    floatx4 acc[16];
    #pragma unroll
    for (int nt = 0; nt < 16; nt++) {
        union { uint4 u4[2]; v8i v; } B0, B1;
        const uint4* p0 = (const uint4*)(wfrag8 + ((size_t)(0 * 16 + nt) * 64 + lane) * 32);
        const uint4* p1 = (const uint4*)(wfrag8 + ((size_t)(1 * 16 + nt) * 64 + lane) * 32);
        B0.u4[0] = p0[0]; B0.u4[1] = p0[1];
        B1.u4[0] = p1[0]; B1.u4[1] = p1[1];
        floatx4 a = __builtin_amdgcn_mfma_scale_f32_16x16x128_f8f6f4(
                        A[0].v, B0.v, zero4, 0, 0, 0, SCALE_Q, 0, SCALE_Q);
        a = __builtin_amdgcn_mfma_scale_f32_16x16x128_f8f6f4(
                        A[1].v, B1.v, a, 0, 0, 0, SCALE_Q, 0, SCALE_Q);
        acc[nt] = a;
    }

    // D: row = w*16 + kg*4 + r (timestep), col = nt*16 + m (unit) -> fp8 x16
    int rloc = w * 16 + kg * 4;
    #pragma unroll
    for (int nt = 0; nt < 16; nt++) {
        #pragma unroll
        for (int r = 0; r < 4; r++) {
            gt[rloc + r][nt * 16 + m] = f2fp8(16.f * acc[nt][r]);
        }
    }
    __syncthreads();

    int rowbase = blockIdx.x * 64;
    #pragma unroll
    for (int r2 = 0; r2 < 16; r2++) {
        int rr = w * 16 + r2;
        uint32_t v = *(const uint32_t*)&gt[rr][lane * 4];
        *(uint32_t*)(xw8 + (size_t)(rowbase + rr) * UN + lane * 4) = v;
    }
}

// ---------------------------------------------------------------------------
// Kernel 3 (v12): R9's proven MX-fp8 scan, xstage now fp8 (16 KB chunk).
// 128 blocks x 256 threads; wave w owns N-tiles 4w..4w+3 (units 64w..64w+63).
// Per step: 4 broadcast ds_read_b128 A-frags + 8 scaled MFMA (4 tiles x
// 2-chain) + select + xf(fp8 dec, off critical path) + poly tanh +
// 1 ds_write_b8 + lgkm-only BAR. No VMEM near barriers.
// ---------------------------------------------------------------------------
__global__ __launch_bounds__(256, 1) void k_rnn(
    const unsigned char* __restrict__ ufrag8, const unsigned char* __restrict__ xw8,
    const float* __restrict__ W1, const float* __restrict__ b1,
    const float* __restrict__ W2, const float* __restrict__ b2,
    float* __restrict__ out)
{
    __shared__ __align__(16) unsigned char hb8[2][256];
    __shared__ __align__(16) unsigned char xstage[64 * 256];   // 16 KB chunk
    __shared__ float hid[32];
    const int t    = threadIdx.x;
    const int lane = t & 63;
    const int w    = t >> 6;
    const int kg   = lane >> 4;
    const int b    = blockIdx.x;

    // U fp8 B-frags -> registers: ufr8[q][kh], tile nt = 4w+q
    v8i ufr8[4][2];
    #pragma unroll
    for (int q = 0; q < 4; q++) {
        #pragma unroll
        for (int kh = 0; kh < 2; kh++) {
            const uint4* p = (const uint4*)(ufrag8 + ((size_t)(kh * 16 + 4 * w + q) * 64 + lane) * 32);
            union { uint4 u4[2]; v8i v; } cvt;
            cvt.u4[0] = p[0]; cvt.u4[1] = p[1];
            ufr8[q][kh] = cvt.v;
        }
    }

    const unsigned char* xwb = xw8 + (size_t)b * TT * UN;
    const int roff = t * 16;   // byte offset of this thread's 16B refresh slice

    // stage chunk 0 (steps 0..63): 256 thr x 4 x 16B = 16 KB
    uint4 xr[4];
    #pragma unroll
    for (int p = 0; p < 4; p++) xr[p] = *(const uint4*)(xwb + roff + p * 4096);
    #pragma unroll
    for (int p = 0; p < 4; p++) *(uint4*)&xstage[roff + p * 4096] = xr[p];

    hb8[0][t] = 0; hb8[1][t] = 0;
    __syncthreads();

    int cur = 0;
    const float c3 = -0.33333334f, c5 = 0.13333334f, c7 = -0.05396825f, c9 = 0.02186949f;
    const floatx4 zero4 = {0.f, 0.f, 0.f, 0.f};
    const int sel = lane >> 4;

    for (int s = 0; s < TT; s++) {
        const int ls = s & 63;
        uint32_t xword = *(const uint32_t*)&xstage[ls * 256 + (t & ~3)];
        float xf = fp8dec(xword, t & 3) * 0.0625f;   // /16

        // A-frags (fp8, 4*h): broadcast 32B reads per k-half
        const unsigned char* hc = hb8[cur];
        union { uint4 u4[2]; v8i v; } A0, A1;
        A0.u4[0] = *(const uint4*)(hc + kg * 32);
        A0.u4[1] = *(const uint4*)(hc + kg * 32 + 16);
        A1.u4[0] = *(const uint4*)(hc + 128 + kg * 32);
        A1.u4[1] = *(const uint4*)(hc + 128 + kg * 32 + 16);

        // 4 tiles, chained K=128 x2 accumulate (R9-proven form)
        float z[4];
        #pragma unroll
        for (int q = 0; q < 4; q++) {
            floatx4 acc = __builtin_amdgcn_mfma_scale_f32_16x16x128_f8f6f4(
                              A0.v, ufr8[q][0], zero4, 0, 0, 0, SCALE_A, 0, SCALE_Q);
            acc = __builtin_amdgcn_mfma_scale_f32_16x16x128_f8f6f4(
                              A1.v, ufr8[q][1], acc, 0, 0, 0, SCALE_A, 0, SCALE_Q);
            z[q] = acc[0];
        }

        float zz = (sel == 0) ? z[0] : (sel == 1) ? z[1] : (sel == 2) ? z[2] : z[3];
        zz += xf;

        float hn;
        if (__builtin_expect(fabsf(zz) > 0.75f, 0)) {
            float e = __expf(2.f * zz);
            hn = 1.f - 2.f * __builtin_amdgcn_rcpf(e + 1.f);
        } else {
            float x2f = zz * zz;
            float p = fmaf(x2f, c9, c7);
            p = fmaf(x2f, p, c5);
            p = fmaf(x2f, p, c3);
            hn = fmaf(zz * x2f, p, zz);
        }

        hb8[cur ^ 1][t] = f2fp8(4.f * hn);

        if (ls == 60 && s + 68 <= TT) {
            const unsigned char* cb = xwb + (size_t)(s + 4) * UN;
            #pragma unroll
            for (int p = 0; p < 4; p++) xr[p] = *(const uint4*)(cb + roff + p * 4096);
        }
        if (ls == 63 && s + 65 <= TT) {
            BAR();
            #pragma unroll
            for (int p = 0; p < 4; p++) *(uint4*)&xstage[roff + p * 4096] = xr[p];
        }
        BAR();
        cur ^= 1;
    }

    // ---- head: hidden = relu(h @ W1 + b1); logits; softmax (h = fp8/4)
    if (t < 32) {
        float a = b1[t];
        for (int k = 0; k < 256; k++) {
            uint32_t wd = *(const uint32_t*)&hb8[cur][k & ~3];
            a += 0.25f * fp8dec(wd, k & 3) * W1[k * 32 + t];
        }
        hid[t] = fmaxf(a, 0.f);
    }
    __syncthreads();
    if (t == 0) {
        float l0 = b2[0], l1 = b2[1];
        #pragma unroll
        for (int i = 0; i < 32; i++) {
            float hv = hid[i];
            l0 += hv * W2[2 * i];
            l1 += hv * W2[2 * i + 1];
        }
        float mx2 = fmaxf(l0, l1);
        float e0 = __expf(l0 - mx2), e1 = __expf(l1 - mx2);
        float inv = 1.f / (e0 + e1);
        out[2 * b]     = e0 * inv;
        out[2 * b + 1] = e1 * inv;
    }
}

extern "C" void kernel_launch(void* const* d_in, const int* in_sizes, int n_in,
                              void* d_out, int out_size, void* d_ws, size_t ws_size,
                              hipStream_t stream) {
    const int*   sent = (const int*)d_in[0];
    const float* emb  = (const float*)d_in[1];
    const float* W    = (const float*)d_in[2];
    const float* U    = (const float*)d_in[3];
    const float* W1   = (const float*)d_in[4];
    const float* b1   = (const float*)d_in[5];
    const float* W2   = (const float*)d_in[6];
    const float* b2   = (const float*)d_in[7];
    float* out = (float*)d_out;

    unsigned char* xw8    = (unsigned char*)d_ws;                                   // 16 MB fp8 [B][T][U]
    unsigned char* wfrag8 = (unsigned char*)d_ws + (size_t)NB * TT * UN;            // 64 KB
    unsigned char* ufrag8 = wfrag8 + (size_t)UN * EM;                               // 64 KB

    k_pack<<<64, 256, 0, stream>>>(W, U, wfrag8, ufrag8);
    k_gemm<<<(NB * TT) / 64, 256, 0, stream>>>(sent, emb, wfrag8, xw8);
    k_rnn<<<NB, 256, 0, stream>>>(ufrag8, xw8, W1, b1, W2, b2, out);
}